// Round 4
// baseline (241.003 us; speedup 1.0000x reference)
//
#include <hip/hip_runtime.h>
#include <math.h>

// B=16, L=200, H=256, heads=4, d=64
#define LQ 200
#define HDIM 256

// 16-lane sum reduction via DPP adds (VALU pipe, no LDS traffic).
// After 4 steps every lane of each 16-lane group holds the group sum.
template <int CTRL>
__device__ __forceinline__ float dpp_add_step(float x) {
    int y = __builtin_amdgcn_update_dpp(0, __float_as_int(x), CTRL, 0xF, 0xF, true);
    return x + __int_as_float(y);
}
__device__ __forceinline__ float reduce16(float x) {
    x = dpp_add_step<0xB1>(x);   // quad_perm xor1
    x = dpp_add_step<0x4E>(x);   // quad_perm xor2
    x = dpp_add_step<0x141>(x);  // row_half_mirror (xor4)
    x = dpp_add_step<0x140>(x);  // row_mirror (xor8)
    return x;
}

// ---------------- Kernel 1: projections + pos-bias folding -------------------
__global__ __launch_bounds__(256) void proj_kernel(
    const float* __restrict__ queries, const float* __restrict__ keys,
    const float* __restrict__ posK, const float* __restrict__ posV,
    const float* __restrict__ Wq, const float* __restrict__ bq,
    const float* __restrict__ Wk, const float* __restrict__ bk,
    const float* __restrict__ Wv, const float* __restrict__ bv,
    float* __restrict__ Qp, float* __restrict__ Ksum, float* __restrict__ Vsum)
{
    __shared__ float qrow[8][HDIM];
    __shared__ float krow[8][HDIM];
    const int t = threadIdx.x;
    const int blk = blockIdx.x;                 // 0..399
    const size_t base = (size_t)blk * 8 * HDIM;

    #pragma unroll
    for (int i = 0; i < 2; ++i) {
        int idx = i * 1024 + t * 4;
        *(float4*)&qrow[0][idx] = *(const float4*)&queries[base + idx];
        *(float4*)&krow[0][idx] = *(const float4*)&keys[base + idx];
    }
    __syncthreads();

    float accQ[8], accK[8], accV[8];
    #pragma unroll
    for (int r = 0; r < 8; ++r) { accQ[r] = 0.f; accK[r] = 0.f; accV[r] = 0.f; }

    const float4* wqp = (const float4*)&Wq[t * HDIM];
    const float4* wkp = (const float4*)&Wk[t * HDIM];
    const float4* wvp = (const float4*)&Wv[t * HDIM];

    for (int k4 = 0; k4 < HDIM / 4; ++k4) {
        float4 wq = wqp[k4], wk = wkp[k4], wv = wvp[k4];
        #pragma unroll
        for (int r = 0; r < 8; ++r) {
            float4 qv = *(const float4*)&qrow[r][k4 * 4];
            float4 kv = *(const float4*)&krow[r][k4 * 4];
            accQ[r] += qv.x * wq.x + qv.y * wq.y + qv.z * wq.z + qv.w * wq.w;
            accK[r] += kv.x * wk.x + kv.y * wk.y + kv.z * wk.z + kv.w * wk.w;
            accV[r] += kv.x * wv.x + kv.y * wv.y + kv.z * wv.z + kv.w * wv.w;
        }
    }

    const float bqv = bq[t], bkv = bk[t], bvv = bv[t];
    #pragma unroll
    for (int r = 0; r < 8; ++r) {
        size_t row = (size_t)blk * 8 + r;
        Qp[row * HDIM + t]   = (accQ[r] + bqv) * 0.125f;   // 1/sqrt(64) folded
        Ksum[row * HDIM + t] = accK[r] + bkv + posK[row * HDIM + t];
        Vsum[row * HDIM + t] = accV[r] + bvv + posV[row * HDIM + t];
    }
}

// ---------------- Kernel 2: fused single-pass attention ---------------------
// One block per (b,l); 4 waves; wave w handles keys m == w (mod 4).
// Lane ln: head h = ln>>4, channel quad c = ln*4. Register-light body +
// __launch_bounds__(256,6) (cap ~85 VGPR -> 6 waves/SIMD) for latency hiding.
// Base pointers are wave-uniform (SGPR) advanced by uniform strides; the only
// per-lane address component is the fixed byte offset c*4.
__global__ __launch_bounds__(256, 6) void attn_fused(
    const float* __restrict__ Qp, const float* __restrict__ Ksum,
    const float* __restrict__ Vsum, const float* __restrict__ tmK,
    const float* __restrict__ tmV, const int* __restrict__ tmask,
    float* __restrict__ out)
{
    __shared__ float outp[4][HDIM];   // per-wave output partials
    __shared__ float Ssh[4][4];       // per-wave, per-head softmax denoms

    const int t = threadIdx.x;
    const int w = t >> 6;
    const int ln = t & 63;
    const int h = ln >> 4;
    const int c = ln * 4;
    const int blk = blockIdx.x;       // b*200 + l
    const int b = blk / LQ;
    const int l = blk - b * LQ;

    const bool rowmask = (tmask[blk] != 0);

    // wave-uniform stream bases (start at m = w)
    const float* pTV = tmV + (size_t)blk * (LQ * HDIM) + w * HDIM;
    const float* pVS = Vsum + (size_t)b * (LQ * HDIM) + w * HDIM;

    float4 acc = {0.f, 0.f, 0.f, 0.f};

    if (rowmask) {
        // ---- exact-uniform row: out = (1/200) * sum_m (Vsum[m] + tmV[m]) ----
        // unroll 2 m-steps (stride 4 each): 4 loads in flight, ~12 live VGPRs
        #pragma unroll 1
        for (int i = 0; i < LQ / 8; ++i) {      // 25 iterations, m = w+8i, w+8i+4
            const float4 a0 = *(const float4*)&pTV[c];
            const float4 b0 = *(const float4*)&pVS[c];
            const float4 a1 = *(const float4*)&pTV[4 * HDIM + c];
            const float4 b1 = *(const float4*)&pVS[4 * HDIM + c];
            acc.x += (a0.x + b0.x) + (a1.x + b1.x);
            acc.y += (a0.y + b0.y) + (a1.y + b1.y);
            acc.z += (a0.z + b0.z) + (a1.z + b1.z);
            acc.w += (a0.w + b0.w) + (a1.w + b1.w);
            pTV += 8 * HDIM;
            pVS += 8 * HDIM;
        }
        *(float4*)&outp[w][c] = acc;
        __syncthreads();
        out[(size_t)blk * HDIM + t] =
            (outp[0][t] + outp[1][t] + outp[2][t] + outp[3][t]) * (1.0f / LQ);
    } else {
        // ---- causal row: m in [0, l], this wave: m = w, w+4, ... ----
        const float* pTK = tmK + (size_t)blk * (LQ * HDIM) + w * HDIM;
        const float* pKS = Ksum + (size_t)b * (LQ * HDIM) + w * HDIM;
        const float4 Q4 = *(const float4*)&Qp[(size_t)blk * HDIM + c];
        const int iters = (l >= w) ? ((l - w) >> 2) + 1 : 0;
        float S = 0.f;

        #pragma unroll 1
        for (int i = 0; i < iters; ++i) {
            const float4 k1 = *(const float4*)&pTK[c];
            const float4 k2 = *(const float4*)&pKS[c];
            const float4 v1 = *(const float4*)&pTV[c];
            const float4 v2 = *(const float4*)&pVS[c];
            float p = Q4.x * (k1.x + k2.x) + Q4.y * (k1.y + k2.y)
                    + Q4.z * (k1.z + k2.z) + Q4.w * (k1.w + k2.w);
            p = reduce16(p);
            const float e = __expf(p);
            acc.x += e * (v1.x + v2.x);
            acc.y += e * (v1.y + v2.y);
            acc.z += e * (v1.z + v2.z);
            acc.w += e * (v1.w + v2.w);
            S += e;
            pTK += 4 * HDIM;
            pKS += 4 * HDIM;
            pTV += 4 * HDIM;
            pVS += 4 * HDIM;
        }

        *(float4*)&outp[w][c] = acc;
        if ((ln & 15) == 0) Ssh[w][h] = S;
        __syncthreads();

        const int hh = t >> 6;   // head owning output channel t
        const float Stot = Ssh[0][hh] + Ssh[1][hh] + Ssh[2][hh] + Ssh[3][hh];
        out[(size_t)blk * HDIM + t] =
            (outp[0][t] + outp[1][t] + outp[2][t] + outp[3][t]) / Stot;
    }
}

// ---------------- launch ----------------------------------------------------
extern "C" void kernel_launch(void* const* d_in, const int* in_sizes, int n_in,
                              void* d_out, int out_size, void* d_ws, size_t ws_size,
                              hipStream_t stream) {
    const float* queries = (const float*)d_in[0];
    const float* keys    = (const float*)d_in[1];
    const int*   tmask   = (const int*)d_in[2];
    // d_in[3] attn_mask: deterministic causal triu(k=1) -> handled analytically
    const float* tmK  = (const float*)d_in[4];
    const float* tmV  = (const float*)d_in[5];
    const float* posK = (const float*)d_in[6];
    const float* posV = (const float*)d_in[7];
    const float* Wq = (const float*)d_in[8];
    const float* bq = (const float*)d_in[9];
    const float* Wk = (const float*)d_in[10];
    const float* bk = (const float*)d_in[11];
    const float* Wv = (const float*)d_in[12];
    const float* bv = (const float*)d_in[13];

    float* ws   = (float*)d_ws;
    float* Qp   = ws;                  // 819200 floats
    float* Ksum = ws + 819200;         // 819200 floats
    float* Vsum = ws + 2 * 819200;     // 819200 floats
    float* out  = (float*)d_out;

    hipLaunchKernelGGL(proj_kernel, dim3(400), dim3(256), 0, stream,
                       queries, keys, posK, posV, Wq, bq, Wk, bk, Wv, bv,
                       Qp, Ksum, Vsum);
    hipLaunchKernelGGL(attn_fused, dim3(3200), dim3(256), 0, stream,
                       Qp, Ksum, Vsum, tmK, tmV, tmask, out);
}

// Round 5
// 236.580 us; speedup vs baseline: 1.0187x; 1.0187x over previous
//
#include <hip/hip_runtime.h>
#include <math.h>

// B=16, L=200, H=256, heads=4, d=64
#define LQ 200
#define HDIM 256

// 16-lane sum reduction via DPP adds (VALU pipe, no LDS traffic).
template <int CTRL>
__device__ __forceinline__ float dpp_add_step(float x) {
    int y = __builtin_amdgcn_update_dpp(0, __float_as_int(x), CTRL, 0xF, 0xF, true);
    return x + __int_as_float(y);
}
__device__ __forceinline__ float reduce16(float x) {
    x = dpp_add_step<0xB1>(x);   // quad_perm xor1
    x = dpp_add_step<0x4E>(x);   // quad_perm xor2
    x = dpp_add_step<0x141>(x);  // row_half_mirror (xor4)
    x = dpp_add_step<0x140>(x);  // row_mirror (xor8)
    return x;
}

// ---------------- Kernel 1: projections + pos-bias folding -------------------
__global__ __launch_bounds__(256) void proj_kernel(
    const float* __restrict__ queries, const float* __restrict__ keys,
    const float* __restrict__ posK, const float* __restrict__ posV,
    const float* __restrict__ Wq, const float* __restrict__ bq,
    const float* __restrict__ Wk, const float* __restrict__ bk,
    const float* __restrict__ Wv, const float* __restrict__ bv,
    float* __restrict__ Qp, float* __restrict__ Ksum, float* __restrict__ Vsum)
{
    __shared__ float qrow[8][HDIM];
    __shared__ float krow[8][HDIM];
    const int t = threadIdx.x;
    const int blk = blockIdx.x;                 // 0..399
    const size_t base = (size_t)blk * 8 * HDIM;

    #pragma unroll
    for (int i = 0; i < 2; ++i) {
        int idx = i * 1024 + t * 4;
        *(float4*)&qrow[0][idx] = *(const float4*)&queries[base + idx];
        *(float4*)&krow[0][idx] = *(const float4*)&keys[base + idx];
    }
    __syncthreads();

    float accQ[8], accK[8], accV[8];
    #pragma unroll
    for (int r = 0; r < 8; ++r) { accQ[r] = 0.f; accK[r] = 0.f; accV[r] = 0.f; }

    const float4* wqp = (const float4*)&Wq[t * HDIM];
    const float4* wkp = (const float4*)&Wk[t * HDIM];
    const float4* wvp = (const float4*)&Wv[t * HDIM];

    for (int k4 = 0; k4 < HDIM / 4; ++k4) {
        float4 wq = wqp[k4], wk = wkp[k4], wv = wvp[k4];
        #pragma unroll
        for (int r = 0; r < 8; ++r) {
            float4 qv = *(const float4*)&qrow[r][k4 * 4];
            float4 kv = *(const float4*)&krow[r][k4 * 4];
            accQ[r] += qv.x * wq.x + qv.y * wq.y + qv.z * wq.z + qv.w * wq.w;
            accK[r] += kv.x * wk.x + kv.y * wk.y + kv.z * wk.z + kv.w * wk.w;
            accV[r] += kv.x * wv.x + kv.y * wv.y + kv.z * wv.z + kv.w * wv.w;
        }
    }

    const float bqv = bq[t], bkv = bk[t], bvv = bv[t];
    #pragma unroll
    for (int r = 0; r < 8; ++r) {
        size_t row = (size_t)blk * 8 + r;
        Qp[row * HDIM + t]   = (accQ[r] + bqv) * 0.125f;   // 1/sqrt(64) folded
        Ksum[row * HDIM + t] = accK[r] + bkv + posK[row * HDIM + t];
        Vsum[row * HDIM + t] = accV[r] + bvv + posV[row * HDIM + t];
    }
}

// ---------------- Kernel 2: fused single-pass attention ---------------------
// One block per (b,l); XCD-swizzled so 400 consecutive rows (2 batches) stay
// on one XCD -> Ksum/Vsum L2-resident per XCD. 4 waves; wave w owns keys
// m == w (mod 4). 1-ahead register prefetch keeps loads in flight during
// compute (compiler emits counted vmcnt waits).
__global__ __launch_bounds__(256) void attn_fused(
    const float* __restrict__ Qp, const float* __restrict__ Ksum,
    const float* __restrict__ Vsum, const float* __restrict__ tmK,
    const float* __restrict__ tmV, const int* __restrict__ tmask,
    float* __restrict__ out)
{
    __shared__ float outp[4][HDIM];   // per-wave output partials
    __shared__ float Ssh[4][4];       // per-wave, per-head softmax denoms

    const int t = threadIdx.x;
    const int w = t >> 6;
    const int ln = t & 63;
    const int h = ln >> 4;
    const int c = ln * 4;
    // bijective XCD swizzle: physical bid%8 = XCD; logical rows contiguous/XCD
    const int bid = blockIdx.x;
    const int blk = (bid & 7) * 400 + (bid >> 3);   // 3200 = 8 * 400
    const int b = blk / LQ;
    const int l = blk - b * LQ;

    const bool rowmask = (tmask[blk] != 0);

    const float* pTV = tmV + (size_t)blk * (LQ * HDIM) + w * HDIM;
    const float* pVS = Vsum + (size_t)b * (LQ * HDIM) + w * HDIM;

    float4 acc = {0.f, 0.f, 0.f, 0.f};

    if (rowmask) {
        // ---- exact-uniform row: out = (1/200) * sum_m (Vsum[m] + tmV[m]) ----
        // pair (m, m+4) per iter, prefetch next pair: 4 loads in flight.
        float4 a0 = *(const float4*)&pTV[c];
        float4 b0 = *(const float4*)&pVS[c];
        float4 a1 = *(const float4*)&pTV[4 * HDIM + c];
        float4 b1 = *(const float4*)&pVS[4 * HDIM + c];
        for (int i = 1; i < LQ / 8; ++i) {     // 24 more pairs
            pTV += 8 * HDIM;
            pVS += 8 * HDIM;
            const float4 na0 = *(const float4*)&pTV[c];
            const float4 nb0 = *(const float4*)&pVS[c];
            const float4 na1 = *(const float4*)&pTV[4 * HDIM + c];
            const float4 nb1 = *(const float4*)&pVS[4 * HDIM + c];
            acc.x += (a0.x + b0.x) + (a1.x + b1.x);
            acc.y += (a0.y + b0.y) + (a1.y + b1.y);
            acc.z += (a0.z + b0.z) + (a1.z + b1.z);
            acc.w += (a0.w + b0.w) + (a1.w + b1.w);
            a0 = na0; b0 = nb0; a1 = na1; b1 = nb1;
        }
        acc.x += (a0.x + b0.x) + (a1.x + b1.x);
        acc.y += (a0.y + b0.y) + (a1.y + b1.y);
        acc.z += (a0.z + b0.z) + (a1.z + b1.z);
        acc.w += (a0.w + b0.w) + (a1.w + b1.w);

        *(float4*)&outp[w][c] = acc;
        __syncthreads();
        out[(size_t)blk * HDIM + t] =
            (outp[0][t] + outp[1][t] + outp[2][t] + outp[3][t]) * (1.0f / LQ);
    } else {
        // ---- causal row: m in [0, l], this wave: m = w, w+4, ... ----
        const float* pTK = tmK + (size_t)blk * (LQ * HDIM) + w * HDIM;
        const float* pKS = Ksum + (size_t)b * (LQ * HDIM) + w * HDIM;
        const float4 Q4 = *(const float4*)&Qp[(size_t)blk * HDIM + c];
        const int n = (l >= w) ? ((l - w) >> 2) + 1 : 0;
        float S = 0.f;

        if (n > 0) {
            float4 k1 = *(const float4*)&pTK[c];
            float4 k2 = *(const float4*)&pKS[c];
            float4 v1 = *(const float4*)&pTV[c];
            float4 v2 = *(const float4*)&pVS[c];
            for (int i = 1; i < n; ++i) {
                pTK += 4 * HDIM; pKS += 4 * HDIM;
                pTV += 4 * HDIM; pVS += 4 * HDIM;
                const float4 nk1 = *(const float4*)&pTK[c];
                const float4 nk2 = *(const float4*)&pKS[c];
                const float4 nv1 = *(const float4*)&pTV[c];
                const float4 nv2 = *(const float4*)&pVS[c];
                float p = Q4.x * (k1.x + k2.x) + Q4.y * (k1.y + k2.y)
                        + Q4.z * (k1.z + k2.z) + Q4.w * (k1.w + k2.w);
                p = reduce16(p);
                const float e = __expf(p);
                acc.x += e * (v1.x + v2.x);
                acc.y += e * (v1.y + v2.y);
                acc.z += e * (v1.z + v2.z);
                acc.w += e * (v1.w + v2.w);
                S += e;
                k1 = nk1; k2 = nk2; v1 = nv1; v2 = nv2;
            }
            float p = Q4.x * (k1.x + k2.x) + Q4.y * (k1.y + k2.y)
                    + Q4.z * (k1.z + k2.z) + Q4.w * (k1.w + k2.w);
            p = reduce16(p);
            const float e = __expf(p);
            acc.x += e * (v1.x + v2.x);
            acc.y += e * (v1.y + v2.y);
            acc.z += e * (v1.z + v2.z);
            acc.w += e * (v1.w + v2.w);
            S += e;
        }

        *(float4*)&outp[w][c] = acc;
        if ((ln & 15) == 0) Ssh[w][h] = S;
        __syncthreads();

        const int hh = t >> 6;   // head owning output channel t
        const float Stot = Ssh[0][hh] + Ssh[1][hh] + Ssh[2][hh] + Ssh[3][hh];
        out[(size_t)blk * HDIM + t] =
            (outp[0][t] + outp[1][t] + outp[2][t] + outp[3][t]) / Stot;
    }
}

// ---------------- launch ----------------------------------------------------
extern "C" void kernel_launch(void* const* d_in, const int* in_sizes, int n_in,
                              void* d_out, int out_size, void* d_ws, size_t ws_size,
                              hipStream_t stream) {
    const float* queries = (const float*)d_in[0];
    const float* keys    = (const float*)d_in[1];
    const int*   tmask   = (const int*)d_in[2];
    // d_in[3] attn_mask: deterministic causal triu(k=1) -> handled analytically
    const float* tmK  = (const float*)d_in[4];
    const float* tmV  = (const float*)d_in[5];
    const float* posK = (const float*)d_in[6];
    const float* posV = (const float*)d_in[7];
    const float* Wq = (const float*)d_in[8];
    const float* bq = (const float*)d_in[9];
    const float* Wk = (const float*)d_in[10];
    const float* bk = (const float*)d_in[11];
    const float* Wv = (const float*)d_in[12];
    const float* bv = (const float*)d_in[13];

    float* ws   = (float*)d_ws;
    float* Qp   = ws;                  // 819200 floats
    float* Ksum = ws + 819200;         // 819200 floats
    float* Vsum = ws + 2 * 819200;     // 819200 floats
    float* out  = (float*)d_out;

    hipLaunchKernelGGL(proj_kernel, dim3(400), dim3(256), 0, stream,
                       queries, keys, posK, posV, Wq, bq, Wk, bk, Wv, bv,
                       Qp, Ksum, Vsum);
    hipLaunchKernelGGL(attn_fused, dim3(3200), dim3(256), 0, stream,
                       Qp, Ksum, Vsum, tmK, tmV, tmask, out);
}

// Round 6
// 230.643 us; speedup vs baseline: 1.0449x; 1.0257x over previous
//
#include <hip/hip_runtime.h>
#include <math.h>

// B=16, L=200, H=256, heads=4, d=64
#define LQ 200
#define HDIM 256
#define G 8        // query rows per group
#define NSTRIP 5   // key strips
#define SLEN 40    // keys per strip
#define NCHUNK 10  // SLEN/4
#define NROW 3200  // B*LQ

// 16-lane sum reduction via DPP adds (VALU pipe).
template <int CTRL>
__device__ __forceinline__ float dpp_add_step(float x) {
    int y = __builtin_amdgcn_update_dpp(0, __float_as_int(x), CTRL, 0xF, 0xF, true);
    return x + __int_as_float(y);
}
__device__ __forceinline__ float reduce16(float x) {
    x = dpp_add_step<0xB1>(x);   // quad_perm xor1
    x = dpp_add_step<0x4E>(x);   // quad_perm xor2
    x = dpp_add_step<0x141>(x);  // row_half_mirror (xor4)
    x = dpp_add_step<0x140>(x);  // row_mirror (xor8)
    return x;
}

// ---------------- Kernel 1: projections + pos-bias folding -------------------
__global__ __launch_bounds__(256) void proj_kernel(
    const float* __restrict__ queries, const float* __restrict__ keys,
    const float* __restrict__ posK, const float* __restrict__ posV,
    const float* __restrict__ Wq, const float* __restrict__ bq,
    const float* __restrict__ Wk, const float* __restrict__ bk,
    const float* __restrict__ Wv, const float* __restrict__ bv,
    float* __restrict__ Qp, float* __restrict__ Ksum, float* __restrict__ Vsum)
{
    __shared__ float qrow[8][HDIM];
    __shared__ float krow[8][HDIM];
    const int t = threadIdx.x;
    const int blk = blockIdx.x;                 // 0..399
    const size_t base = (size_t)blk * 8 * HDIM;

    #pragma unroll
    for (int i = 0; i < 2; ++i) {
        int idx = i * 1024 + t * 4;
        *(float4*)&qrow[0][idx] = *(const float4*)&queries[base + idx];
        *(float4*)&krow[0][idx] = *(const float4*)&keys[base + idx];
    }
    __syncthreads();

    float accQ[8], accK[8], accV[8];
    #pragma unroll
    for (int r = 0; r < 8; ++r) { accQ[r] = 0.f; accK[r] = 0.f; accV[r] = 0.f; }

    const float4* wqp = (const float4*)&Wq[t * HDIM];
    const float4* wkp = (const float4*)&Wk[t * HDIM];
    const float4* wvp = (const float4*)&Wv[t * HDIM];

    for (int k4 = 0; k4 < HDIM / 4; ++k4) {
        float4 wq = wqp[k4], wk = wkp[k4], wv = wvp[k4];
        #pragma unroll
        for (int r = 0; r < 8; ++r) {
            float4 qv = *(const float4*)&qrow[r][k4 * 4];
            float4 kv = *(const float4*)&krow[r][k4 * 4];
            accQ[r] += qv.x * wq.x + qv.y * wq.y + qv.z * wq.z + qv.w * wq.w;
            accK[r] += kv.x * wk.x + kv.y * wk.y + kv.z * wk.z + kv.w * wk.w;
            accV[r] += kv.x * wv.x + kv.y * wv.y + kv.z * wv.z + kv.w * wv.w;
        }
    }

    const float bqv = bq[t], bkv = bk[t], bvv = bv[t];
    #pragma unroll
    for (int r = 0; r < 8; ++r) {
        size_t row = (size_t)blk * 8 + r;
        Qp[row * HDIM + t]   = (accQ[r] + bqv) * 0.125f;   // 1/sqrt(64) folded
        Ksum[row * HDIM + t] = accK[r] + bkv + posK[row * HDIM + t];
        Vsum[row * HDIM + t] = accV[r] + bvv + posV[row * HDIM + t];
    }
}

// ---------------- Kernel 2: grouped partial attention -----------------------
// Block = (group of 8 query rows) x (strip of 40 keys). 2000 uniform blocks.
// 4 waves; wave w owns rows l0+2w, l0+2w+1. Per 4-key chunk, wave w stages
// Ksum[m0+w] & Vsum[m0+w] into LDS (loaded ONCE per group instead of once
// per row: KS/VS global traffic /8). Double-buffered, 1 barrier/chunk.
// Partial (acc, S) per row -> workspace; combine kernel normalizes.
__global__ __launch_bounds__(256) void attn_part(
    const float* __restrict__ Qp, const float* __restrict__ Ksum,
    const float* __restrict__ Vsum, const float* __restrict__ tmK,
    const float* __restrict__ tmV, const int* __restrict__ tmask,
    float* __restrict__ pacc, float* __restrict__ pS)
{
    __shared__ float ks[2][4][HDIM];
    __shared__ float vs[2][4][HDIM];

    const int t = threadIdx.x;
    const int w = t >> 6;
    const int ln = t & 63;
    const int c = ln * 4;
    // XCD swizzle (2000 % 8 == 0): 250 consecutive logical blocks per XCD
    const int bid = blockIdx.x;
    const int blk = (bid & 7) * 250 + (bid >> 3);
    const int g = blk / NSTRIP;            // row group 0..399
    const int s = blk - g * NSTRIP;        // strip 0..4
    const int b = g / 25;
    const int l0 = (g - b * 25) * G;
    const int m0 = s * SLEN;

    const int r0 = l0 + 2 * w;             // this wave's two rows
    const int r1 = r0 + 1;
    const size_t rowsz = (size_t)LQ * HDIM;
    const float* KS = Ksum + (size_t)b * rowsz;
    const float* VS = Vsum + (size_t)b * rowsz;
    const float* tK0 = tmK + ((size_t)(b * LQ + r0)) * rowsz;
    const float* tV0 = tmV + ((size_t)(b * LQ + r0)) * rowsz;
    const float* tK1 = tmK + ((size_t)(b * LQ + r1)) * rowsz;
    const float* tV1 = tmV + ((size_t)(b * LQ + r1)) * rowsz;
    const bool mask0 = (tmask[b * LQ + r0] != 0);
    const bool mask1 = (tmask[b * LQ + r1] != 0);
    const float4 Q0 = *(const float4*)&Qp[((size_t)(b * LQ + r0)) * HDIM + c];
    const float4 Q1 = *(const float4*)&Qp[((size_t)(b * LQ + r1)) * HDIM + c];

    float4 acc0 = {0.f, 0.f, 0.f, 0.f}, acc1 = {0.f, 0.f, 0.f, 0.f};
    float S0 = 0.f, S1 = 0.f;

    // stage chunk `ch` into buffer `buf`: wave w loads key row m0+ch*4+w
    auto stage = [&](int buf, int ch) {
        const size_t mo = (size_t)(m0 + ch * 4 + w) * HDIM + c;
        const float4 kq = *(const float4*)&KS[mo];
        const float4 vq = *(const float4*)&VS[mo];
        *(float4*)&ks[buf][w][c] = kq;
        *(float4*)&vs[buf][w][c] = vq;
    };

    stage(0, 0);
    __syncthreads();

    for (int ch = 0; ch < NCHUNK; ++ch) {
        const int cur = ch & 1;
        if (ch + 1 < NCHUNK) stage(cur ^ 1, ch + 1);

        #pragma unroll
        for (int mm = 0; mm < 4; ++mm) {
            const int m = m0 + ch * 4 + mm;
            // row 0 (predicates wave-uniform)
            if (mask0 || m <= r0) {
                const float4 v1 = *(const float4*)&tV0[(size_t)m * HDIM + c];
                const float4 vsm = *(const float4*)&vs[cur][mm][c];
                float e;
                if (!mask0) {
                    const float4 k1 = *(const float4*)&tK0[(size_t)m * HDIM + c];
                    const float4 ksm = *(const float4*)&ks[cur][mm][c];
                    float p = Q0.x * (k1.x + ksm.x) + Q0.y * (k1.y + ksm.y)
                            + Q0.z * (k1.z + ksm.z) + Q0.w * (k1.w + ksm.w);
                    p = reduce16(p);
                    e = __expf(p);
                } else e = 1.0f;
                acc0.x += e * (v1.x + vsm.x);
                acc0.y += e * (v1.y + vsm.y);
                acc0.z += e * (v1.z + vsm.z);
                acc0.w += e * (v1.w + vsm.w);
                S0 += e;
            }
            // row 1
            if (mask1 || m <= r1) {
                const float4 v1 = *(const float4*)&tV1[(size_t)m * HDIM + c];
                const float4 vsm = *(const float4*)&vs[cur][mm][c];
                float e;
                if (!mask1) {
                    const float4 k1 = *(const float4*)&tK1[(size_t)m * HDIM + c];
                    const float4 ksm = *(const float4*)&ks[cur][mm][c];
                    float p = Q1.x * (k1.x + ksm.x) + Q1.y * (k1.y + ksm.y)
                            + Q1.z * (k1.z + ksm.z) + Q1.w * (k1.w + ksm.w);
                    p = reduce16(p);
                    e = __expf(p);
                } else e = 1.0f;
                acc1.x += e * (v1.x + vsm.x);
                acc1.y += e * (v1.y + vsm.y);
                acc1.z += e * (v1.z + vsm.z);
                acc1.w += e * (v1.w + vsm.w);
                S1 += e;
            }
        }
        __syncthreads();
    }

    // write partials: pacc[s][row][HDIM], pS[s][row][4]
    const int row0 = b * LQ + r0;
    const int row1 = b * LQ + r1;
    *(float4*)&pacc[((size_t)s * NROW + row0) * HDIM + c] = acc0;
    *(float4*)&pacc[((size_t)s * NROW + row1) * HDIM + c] = acc1;
    if ((ln & 15) == 0) {
        pS[((size_t)s * NROW + row0) * 4 + (ln >> 4)] = S0;
        pS[((size_t)s * NROW + row1) * 4 + (ln >> 4)] = S1;
    }
}

// ---------------- Kernel 3: combine strips + normalize ----------------------
__global__ __launch_bounds__(256) void combine_kernel(
    const float* __restrict__ pacc, const float* __restrict__ pS,
    float* __restrict__ out)
{
    const int row = blockIdx.x;       // 0..3199
    const int t = threadIdx.x;        // channel
    const int h = t >> 6;
    float a = 0.f, S = 0.f;
    #pragma unroll
    for (int s = 0; s < NSTRIP; ++s) {
        a += pacc[((size_t)s * NROW + row) * HDIM + t];
        S += pS[((size_t)s * NROW + row) * 4 + h];
    }
    out[(size_t)row * HDIM + t] = a / S;
}

// ---------------- launch ----------------------------------------------------
extern "C" void kernel_launch(void* const* d_in, const int* in_sizes, int n_in,
                              void* d_out, int out_size, void* d_ws, size_t ws_size,
                              hipStream_t stream) {
    const float* queries = (const float*)d_in[0];
    const float* keys    = (const float*)d_in[1];
    const int*   tmask   = (const int*)d_in[2];
    // d_in[3] attn_mask: deterministic causal triu(k=1) -> handled analytically
    const float* tmK  = (const float*)d_in[4];
    const float* tmV  = (const float*)d_in[5];
    const float* posK = (const float*)d_in[6];
    const float* posV = (const float*)d_in[7];
    const float* Wq = (const float*)d_in[8];
    const float* bq = (const float*)d_in[9];
    const float* Wk = (const float*)d_in[10];
    const float* bk = (const float*)d_in[11];
    const float* Wv = (const float*)d_in[12];
    const float* bv = (const float*)d_in[13];

    float* ws   = (float*)d_ws;
    float* Qp   = ws;                        // 819200 floats
    float* Ksum = ws + 819200;               // 819200
    float* Vsum = ws + 2 * 819200;           // 819200
    float* pacc = ws + 3 * 819200;           // 5*3200*256 = 4,096,000
    float* pS   = pacc + (size_t)NSTRIP * NROW * HDIM;  // 5*3200*4 = 64,000
    float* out  = (float*)d_out;

    hipLaunchKernelGGL(proj_kernel, dim3(400), dim3(256), 0, stream,
                       queries, keys, posK, posV, Wq, bq, Wk, bk, Wv, bv,
                       Qp, Ksum, Vsum);
    hipLaunchKernelGGL(attn_part, dim3(400 * NSTRIP), dim3(256), 0, stream,
                       Qp, Ksum, Vsum, tmK, tmV, tmask, pacc, pS);
    hipLaunchKernelGGL(combine_kernel, dim3(NROW), dim3(256), 0, stream,
                       pacc, pS, out);
}